// Round 17
// baseline (35.860 us; speedup 1.0000x reference)
//
#include <hip/hip_runtime.h>
#include <hip/hip_bf16.h>

#define BLK 256
#define CH 4

// Quaternion (.x=w, .y=v1, .z=v2, .w=v3) representing SU(2) matrix w*I - i*(v.sigma)
// with sigma = (pauli0, pauli1, pauli2) from the reference; e_a = -i*sigma_a satisfy
// the quaternion algebra, so Hamilton product == matrix product.
// qmul(A,B) == A@B (A is the LATER factor).
__device__ __forceinline__ float4 qmul(const float4 A, const float4 B) {
    return make_float4(
        A.x*B.x - A.y*B.y - A.z*B.z - A.w*B.w,
        A.x*B.y + B.x*A.y + A.z*B.w - A.w*B.z,
        A.x*B.z + B.x*A.z + A.w*B.y - A.y*B.w,
        A.x*B.w + B.x*A.w + A.y*B.z - A.z*B.y);
}

__device__ __forceinline__ float4 qid() { return make_float4(1.f, 0.f, 0.f, 0.f); }

__device__ __forceinline__ float4 qnorm(const float4 q) {
    float n = rsqrtf(q.x*q.x + q.y*q.y + q.z*q.z + q.w*q.w);
    return make_float4(q.x*n, q.y*n, q.z*n, q.w*n);
}

// Per-step rotation quat: al = 0.01*alpha, theta=|al|, quat=(cos th, sinc(th)*al).
// theta <= ~0.07 here, so 4th-order Taylor is exact to ~1e-10.
__device__ __forceinline__ float4 dquat(float a0, float a1, float a2) {
    float x = a0 * 0.01f, y = a1 * 0.01f, z = a2 * 0.01f;
    float t2 = x*x + y*y + z*z;
    float c = 1.f - t2 * (0.5f - t2 * (1.f / 24.f));
    float f = 1.f - t2 * ((1.f / 6.f) - t2 * (1.f / 120.f));
    return make_float4(c, f*x, f*y, f*z);
}

// Apply M (quat) to complex 2-vector; returns (re0, im0, re1, im1).
// M = [[w - i v1, -v3 - i v2],[v3 - i v2, w + i v1]]
__device__ __forceinline__ float4 qapply(const float4 m, float s0r, float s1r,
                                         float s0i, float s1i) {
    float w = m.x, v1 = m.y, v2 = m.z, v3 = m.w;
    return make_float4(
        w*s0r + v1*s0i - v3*s1r + v2*s1i,
        w*s0i - v1*s0r - v2*s1r - v3*s1i,
        v3*s0r + v2*s0i + w*s1r - v1*s1i,
        v3*s0i - v2*s0r + w*s1i + v1*s1r);
}

__device__ __forceinline__ float4 shfl_up4(const float4 v, int s) {
    return make_float4(__shfl_up(v.x, s), __shfl_up(v.y, s),
                       __shfl_up(v.z, s), __shfl_up(v.w, s));
}
__device__ __forceinline__ float4 shfl_down4(const float4 v, int s) {
    return make_float4(__shfl_down(v.x, s), __shfl_down(v.y, s),
                       __shfl_down(v.z, s), __shfl_down(v.w, s));
}

// Wave-ordered descending product: lane 0 receives c[63] @ c[62] @ ... @ c[0].
__device__ __forceinline__ float4 wave_prod_desc(float4 c) {
    #pragma unroll
    for (int s = 1; s < 64; s <<= 1) {
        float4 u = shfl_down4(c, s);
        c = qmul(u, c);   // segment = upper-half @ lower-half
    }
    return c;
}

// Wave-level INCLUSIVE ordered scan: lane l ends with c[l]@...@c[0].
__device__ __forceinline__ float4 wave_scan_incl(float4 v, int lane) {
    #pragma unroll
    for (int s = 1; s < 64; s <<= 1) {
        float4 u = shfl_up4(v, s);
        if (lane >= s) v = qmul(v, u);
    }
    return v;
}

// Chunk quats kept in registers + tree product (depth 2): (d3@d2)@(d1@d0).
__device__ __forceinline__ float4 chunk_quats(const float* __restrict__ al,
                                              long long t, long long T,
                                              long long nchunk, float4* d, bool& full) {
    full = false;
    if (t >= nchunk) {
        #pragma unroll
        for (int j = 0; j < CH; ++j) d[j] = qid();
        return qid();
    }
    if ((t + 1) * CH <= T) {
        full = true;
        const float4* ap = reinterpret_cast<const float4*>(al) + (size_t)t * 3;
        float4 v0 = ap[0], v1 = ap[1], v2 = ap[2];
        d[0] = dquat(v0.x, v0.y, v0.z);
        d[1] = dquat(v0.w, v1.x, v1.y);
        d[2] = dquat(v1.z, v1.w, v2.x);
        d[3] = dquat(v2.y, v2.z, v2.w);
    } else {
        #pragma unroll
        for (int j = 0; j < CH; ++j) {
            long long k = t * CH + j;
            d[j] = (k < T) ? dquat(al[k*3], al[k*3+1], al[k*3+2]) : qid();
        }
    }
    float4 q = qmul(qmul(d[3], d[2]), qmul(d[1], d[0]));
    return qnorm(q);
}

__device__ __forceinline__ float4 chunk_prod(const float* __restrict__ al,
                                             long long t, long long T,
                                             long long nchunk) {
    float4 d[CH];
    bool full;
    return chunk_quats(al, t, T, nchunk, d, full);
}

// Tail-path epilogue (partial chunks). OUTPUT: f32 real parts [T,2].
__device__ __forceinline__ void apply_and_store_tail(
    const float4* d, float4 run, long long t, long long T,
    const float* __restrict__ sre, const float* __restrict__ sim,
    float* __restrict__ outf) {
    float2* op2 = reinterpret_cast<float2*>(outf);
    #pragma unroll
    for (int j = 0; j < CH; ++j) {
        long long k = t * CH + j;
        if (k < T) {
            run = qmul(d[j], run);
            float4 p = qapply(run, sre[k*2], sre[k*2+1], sim[k*2], sim[k*2+1]);
            op2[k] = make_float2(p.x, p.z);
        }
    }
}

// K1: per-block aggregate via wave shfl-tree reduce (1 barrier).
__global__ void __launch_bounds__(BLK) pmd_k1(
    const float* __restrict__ al, float4* __restrict__ A,
    long long T, long long nchunk) {
    __shared__ float4 sW[BLK / 64];
    const int tid = threadIdx.x, lane = tid & 63, wid = tid >> 6;
    const long long t = (long long)blockIdx.x * BLK + tid;
    float4 q = chunk_prod(al, t, T, nchunk);
    float4 wp = wave_prod_desc(q);
    if (lane == 0) sW[wid] = wp;
    __syncthreads();
    if (tid == 0) {
        float4 a = qmul(sW[1], sW[0]);
        a = qmul(sW[2], a);
        a = qmul(sW[3], a);
        A[blockIdx.x] = qnorm(a);
    }
}

// K2: ONE block, parallel scan of the nblk aggregates.
// Thread owns EPT consecutive entries; EB[idx] = qnorm(A[idx-1]@...@A[0]@q0).
template<int EPT>
__global__ void __launch_bounds__(BLK) pmd_k2(
    const float4* __restrict__ A, float4* __restrict__ EB,
    const float* __restrict__ j0re, const float* __restrict__ j0im, int nblk) {
    __shared__ float4 sW[BLK / 64];
    const int tid = threadIdx.x, lane = tid & 63, wid = tid >> 6;
    const int t0 = tid * EPT;
    float4 excl[EPT];
    float4 run = qid();
    #pragma unroll
    for (int e = 0; e < EPT; ++e) {
        excl[e] = run;
        if (t0 + e < nblk) run = qmul(A[t0 + e], run);
    }
    float4 v = wave_scan_incl(run, lane);
    if (lane == 63) sW[wid] = v;
    __syncthreads();
    float4 P = qid();
    for (int w = 0; w < wid; ++w) P = qmul(sW[w], P);
    float4 vprev = shfl_up4(v, 1);
    float4 texcl = (lane == 0) ? P : qmul(vprev, P);  // product of all earlier threads
    // q0 from J0 = [[w - i v1, -v3 - i v2],[v3 - i v2, w + i v1]]
    float4 q0 = make_float4(j0re[0], -j0im[0], -j0im[1], -j0re[1]);
    float4 base = qmul(texcl, q0);
    #pragma unroll
    for (int e = 0; e < EPT; ++e) {
        if (t0 + e < nblk) EB[t0 + e] = qnorm(qmul(excl[e], base));
    }
}

// K3: EB + signal issued early (latency hides under the scan); chunk quats +
// wave scan + 1 barrier; ILP epilogue (independent prefix composes) with
// regular cached stores (L3 absorbs output; NT stores 12x slower, r15).
__global__ void __launch_bounds__(BLK) pmd_k3(
    const float* __restrict__ al, const float* __restrict__ sre,
    const float* __restrict__ sim, const float4* __restrict__ EB,
    float* __restrict__ outf, long long T, long long nchunk) {
    __shared__ float4 sW[BLK / 64];
    const int tid = threadIdx.x, lane = tid & 63, wid = tid >> 6;
    const int b = blockIdx.x;
    const long long t = (long long)b * BLK + tid;

    float4 eb = EB[b];   // same addr across block -> broadcast
    bool pre = (t < nchunk) && ((t + 1) * CH <= T);
    float4 r0, r1, i0, i1;
    if (pre) {
        const float4* rp = reinterpret_cast<const float4*>(sre) + (size_t)t * 2;
        const float4* ip = reinterpret_cast<const float4*>(sim) + (size_t)t * 2;
        r0 = rp[0]; r1 = rp[1];
        i0 = ip[0]; i1 = ip[1];
    }

    float4 d[CH];
    bool full;
    float4 q = chunk_quats(al, t, T, nchunk, d, full);
    float4 v = wave_scan_incl(q, lane);
    if (lane == 63) sW[wid] = v;
    __syncthreads();
    float4 P = qid();
    for (int w = 0; w < wid; ++w) P = qmul(sW[w], P);
    float4 vprev = shfl_up4(v, 1);
    float4 Xv = (lane == 0) ? P : qmul(vprev, P);
    float4 run = qmul(Xv, eb);

    if (pre) {
        // Prefix quats (depth 2), then 4 INDEPENDENT composes + applies.
        float4 pre1 = qmul(d[1], d[0]);
        float4 pre2 = qmul(d[2], pre1);
        float4 pre3 = qmul(d[3], pre2);
        float4 m0 = qmul(d[0], run);
        float4 m1 = qmul(pre1, run);
        float4 m2 = qmul(pre2, run);
        float4 m3 = qmul(pre3, run);
        float4 p0 = qapply(m0, r0.x, r0.y, i0.x, i0.y);
        float4 p1 = qapply(m1, r0.z, r0.w, i0.z, i0.w);
        float4 p2 = qapply(m2, r1.x, r1.y, i1.x, i1.y);
        float4 p3 = qapply(m3, r1.z, r1.w, i1.z, i1.w);
        float4* op = reinterpret_cast<float4*>(outf) + (size_t)t * 2;
        op[0] = make_float4(p0.x, p0.z, p1.x, p1.z);
        op[1] = make_float4(p2.x, p2.z, p3.x, p3.z);
    } else if (t < nchunk) {
        apply_and_store_tail(d, run, t, T, sre, sim, outf);
    }
}

// Zero-workspace fallback: one block walks the whole sequence in segments.
__global__ void __launch_bounds__(BLK) pmd_mono(
    const float* __restrict__ al, const float* __restrict__ sre,
    const float* __restrict__ sim, const float* __restrict__ j0re,
    const float* __restrict__ j0im, float* __restrict__ outf, long long T) {
    __shared__ float4 sW[BLK / 64];
    __shared__ float4 sbase;
    const int tid = threadIdx.x, lane = tid & 63, wid = tid >> 6;
    if (tid == 0)
        sbase = make_float4(j0re[0], -j0im[0], -j0im[1], -j0re[1]);
    __syncthreads();
    const long long nchunk = (T + CH - 1) / CH;
    for (long long c0 = 0; c0 < nchunk; c0 += BLK) {
        const long long t = c0 + tid;
        float4 d[CH];
        bool full;
        float4 q = chunk_quats(al, t, T, nchunk, d, full);
        float4 v = wave_scan_incl(q, lane);
        if (lane == 63) sW[wid] = v;
        __syncthreads();
        float4 P = qid();
        for (int w = 0; w < wid; ++w) P = qmul(sW[w], P);
        float4 vprev = shfl_up4(v, 1);
        float4 Xv = (lane == 0) ? P : qmul(vprev, P);
        float4 base = sbase;
        __syncthreads();
        if (tid == BLK - 1) sbase = qnorm(qmul(qmul(v, P), base));
        if (t < nchunk) {
            float4 run = qmul(Xv, base);
            apply_and_store_tail(d, run, t, T, sre, sim, outf);
        }
        __syncthreads();
    }
}

extern "C" void kernel_launch(void* const* d_in, const int* in_sizes, int n_in,
                              void* d_out, int out_size, void* d_ws, size_t ws_size,
                              hipStream_t stream) {
    const float* sre  = (const float*)d_in[0];
    const float* sim  = (const float*)d_in[1];
    const float* al   = (const float*)d_in[2];
    const float* j0re = (const float*)d_in[3];
    const float* j0im = (const float*)d_in[4];
    float* outf = (float*)d_out;   // f32 out, real parts [T,2]
    long long T = (long long)in_sizes[2] / 3;
    if (T <= 0) return;

    long long nchunk = (T + CH - 1) / CH;
    long long nblkLL = (nchunk + BLK - 1) / BLK;
    size_t need = (size_t)(2 * nblkLL) * sizeof(float4);

    if (ws_size >= need && nblkLL <= (long long)BLK * 16) {
        int nblk = (int)nblkLL;
        float4* A  = (float4*)d_ws;
        float4* EB = A + nblk;
        pmd_k1<<<nblk, BLK, 0, stream>>>(al, A, T, nchunk);
        if      (nblk <= BLK)      pmd_k2<1> <<<1, BLK, 0, stream>>>(A, EB, j0re, j0im, nblk);
        else if (nblk <= 2 * BLK)  pmd_k2<2> <<<1, BLK, 0, stream>>>(A, EB, j0re, j0im, nblk);
        else if (nblk <= 4 * BLK)  pmd_k2<4> <<<1, BLK, 0, stream>>>(A, EB, j0re, j0im, nblk);
        else if (nblk <= 8 * BLK)  pmd_k2<8> <<<1, BLK, 0, stream>>>(A, EB, j0re, j0im, nblk);
        else                       pmd_k2<16><<<1, BLK, 0, stream>>>(A, EB, j0re, j0im, nblk);
        pmd_k3<<<nblk, BLK, 0, stream>>>(al, sre, sim, EB, outf, T, nchunk);
    } else {
        pmd_mono<<<1, BLK, 0, stream>>>(al, sre, sim, j0re, j0im, outf, T);
    }
}

// Round 18
// 28.781 us; speedup vs baseline: 1.2460x; 1.2460x over previous
//
#include <hip/hip_runtime.h>
#include <hip/hip_bf16.h>

#define BLK 256
#define CH 8

// Quaternion (.x=w, .y=v1, .z=v2, .w=v3) representing SU(2) matrix w*I - i*(v.sigma)
// with sigma = (pauli0, pauli1, pauli2) from the reference; e_a = -i*sigma_a satisfy
// the quaternion algebra, so Hamilton product == matrix product.
// qmul(A,B) == A@B (A is the LATER factor).
__device__ __forceinline__ float4 qmul(const float4 A, const float4 B) {
    return make_float4(
        A.x*B.x - A.y*B.y - A.z*B.z - A.w*B.w,
        A.x*B.y + B.x*A.y + A.z*B.w - A.w*B.z,
        A.x*B.z + B.x*A.z + A.w*B.y - A.y*B.w,
        A.x*B.w + B.x*A.w + A.y*B.z - A.z*B.y);
}

__device__ __forceinline__ float4 qid() { return make_float4(1.f, 0.f, 0.f, 0.f); }

__device__ __forceinline__ float4 qnorm(const float4 q) {
    float n = rsqrtf(q.x*q.x + q.y*q.y + q.z*q.z + q.w*q.w);
    return make_float4(q.x*n, q.y*n, q.z*n, q.w*n);
}

// Per-step rotation quat: al = 0.01*alpha, theta=|al|, quat=(cos th, sinc(th)*al).
// theta <= ~0.07 here, so 4th-order Taylor is exact to ~1e-10.
__device__ __forceinline__ float4 dquat(float a0, float a1, float a2) {
    float x = a0 * 0.01f, y = a1 * 0.01f, z = a2 * 0.01f;
    float t2 = x*x + y*y + z*z;
    float c = 1.f - t2 * (0.5f - t2 * (1.f / 24.f));
    float f = 1.f - t2 * ((1.f / 6.f) - t2 * (1.f / 120.f));
    return make_float4(c, f*x, f*y, f*z);
}

// Apply M (quat) to complex 2-vector; returns (re0, im0, re1, im1).
// M = [[w - i v1, -v3 - i v2],[v3 - i v2, w + i v1]]
__device__ __forceinline__ float4 qapply(const float4 m, float s0r, float s1r,
                                         float s0i, float s1i) {
    float w = m.x, v1 = m.y, v2 = m.z, v3 = m.w;
    return make_float4(
        w*s0r + v1*s0i - v3*s1r + v2*s1i,
        w*s0i - v1*s0r - v2*s1r - v3*s1i,
        v3*s0r + v2*s0i + w*s1r - v1*s1i,
        v3*s0i - v2*s0r + w*s1i + v1*s1r);
}

__device__ __forceinline__ float4 shfl_up4(const float4 v, int s) {
    return make_float4(__shfl_up(v.x, s), __shfl_up(v.y, s),
                       __shfl_up(v.z, s), __shfl_up(v.w, s));
}
__device__ __forceinline__ float4 shfl_down4(const float4 v, int s) {
    return make_float4(__shfl_down(v.x, s), __shfl_down(v.y, s),
                       __shfl_down(v.z, s), __shfl_down(v.w, s));
}

// Wave-ordered descending product: lane 0 receives c[63] @ c[62] @ ... @ c[0].
__device__ __forceinline__ float4 wave_prod_desc(float4 c) {
    #pragma unroll
    for (int s = 1; s < 64; s <<= 1) {
        float4 u = shfl_down4(c, s);
        c = qmul(u, c);   // segment = upper-half @ lower-half
    }
    return c;
}

// Wave-level INCLUSIVE ordered scan: lane l ends with c[l]@...@c[0].
__device__ __forceinline__ float4 wave_scan_incl(float4 v, int lane) {
    #pragma unroll
    for (int s = 1; s < 64; s <<= 1) {
        float4 u = shfl_up4(v, s);
        if (lane >= s) v = qmul(v, u);
    }
    return v;
}

// Chunk quats kept in registers + product (d[CH-1]@...@d[0]).
__device__ __forceinline__ float4 chunk_quats(const float* __restrict__ al,
                                              long long t, long long T,
                                              long long nchunk, float4* d, bool& full) {
    float4 q = qid();
    full = false;
    if (t >= nchunk) {
        #pragma unroll
        for (int j = 0; j < CH; ++j) d[j] = qid();
        return q;
    }
    if ((t + 1) * CH <= T) {
        full = true;
        const float4* ap = reinterpret_cast<const float4*>(al) + (size_t)t * 6;
        float4 v0 = ap[0], v1 = ap[1], v2 = ap[2];
        float4 v3 = ap[3], v4 = ap[4], v5 = ap[5];
        d[0] = dquat(v0.x, v0.y, v0.z);
        d[1] = dquat(v0.w, v1.x, v1.y);
        d[2] = dquat(v1.z, v1.w, v2.x);
        d[3] = dquat(v2.y, v2.z, v2.w);
        d[4] = dquat(v3.x, v3.y, v3.z);
        d[5] = dquat(v3.w, v4.x, v4.y);
        d[6] = dquat(v4.z, v4.w, v5.x);
        d[7] = dquat(v5.y, v5.z, v5.w);
    } else {
        #pragma unroll
        for (int j = 0; j < CH; ++j) {
            long long k = t * CH + j;
            d[j] = (k < T) ? dquat(al[k*3], al[k*3+1], al[k*3+2]) : qid();
        }
    }
    #pragma unroll
    for (int j = 0; j < CH; ++j) q = qmul(d[j], q);
    return qnorm(q);
}

// Chunk product only — for K1.
__device__ __forceinline__ float4 chunk_prod(const float* __restrict__ al,
                                             long long t, long long T,
                                             long long nchunk) {
    float4 d[CH];
    bool full;
    return chunk_quats(al, t, T, nchunk, d, full);
}

// Epilogue. OUTPUT: float32, real parts only, [T,2] row-major:
// outf[2k] = Re(out0(k)), outf[2k+1] = Re(out1(k)).
__device__ __forceinline__ void apply_and_store(
    const float4* d, float4 run, bool full, long long t, long long T,
    const float* __restrict__ sre, const float* __restrict__ sim,
    float* __restrict__ outf) {
    if (full) {
        const float4* rp = reinterpret_cast<const float4*>(sre) + (size_t)t * 4;
        const float4* ip = reinterpret_cast<const float4*>(sim) + (size_t)t * 4;
        float4* op = reinterpret_cast<float4*>(outf) + (size_t)t * 4;
        float4 r0 = rp[0], r1 = rp[1], r2 = rp[2], r3 = rp[3];
        float4 i0 = ip[0], i1 = ip[1], i2 = ip[2], i3 = ip[3];
        float4 p0, p1;
        run = qmul(d[0], run); p0 = qapply(run, r0.x, r0.y, i0.x, i0.y);
        run = qmul(d[1], run); p1 = qapply(run, r0.z, r0.w, i0.z, i0.w);
        op[0] = make_float4(p0.x, p0.z, p1.x, p1.z);
        run = qmul(d[2], run); p0 = qapply(run, r1.x, r1.y, i1.x, i1.y);
        run = qmul(d[3], run); p1 = qapply(run, r1.z, r1.w, i1.z, i1.w);
        op[1] = make_float4(p0.x, p0.z, p1.x, p1.z);
        run = qmul(d[4], run); p0 = qapply(run, r2.x, r2.y, i2.x, i2.y);
        run = qmul(d[5], run); p1 = qapply(run, r2.z, r2.w, i2.z, i2.w);
        op[2] = make_float4(p0.x, p0.z, p1.x, p1.z);
        run = qmul(d[6], run); p0 = qapply(run, r3.x, r3.y, i3.x, i3.y);
        run = qmul(d[7], run); p1 = qapply(run, r3.z, r3.w, i3.z, i3.w);
        op[3] = make_float4(p0.x, p0.z, p1.x, p1.z);
    } else {
        float2* op2 = reinterpret_cast<float2*>(outf);
        #pragma unroll
        for (int j = 0; j < CH; ++j) {
            long long k = t * CH + j;
            if (k < T) {
                run = qmul(d[j], run);
                float4 p = qapply(run, sre[k*2], sre[k*2+1], sim[k*2], sim[k*2+1]);
                op2[k] = make_float2(p.x, p.z);
            }
        }
    }
}

// K1: per-block aggregate via wave shfl-tree reduce (1 barrier).
__global__ void __launch_bounds__(BLK) pmd_k1(
    const float* __restrict__ al, float4* __restrict__ A,
    long long T, long long nchunk) {
    __shared__ float4 sW[BLK / 64];
    const int tid = threadIdx.x, lane = tid & 63, wid = tid >> 6;
    const long long t = (long long)blockIdx.x * BLK + tid;
    float4 q = chunk_prod(al, t, T, nchunk);
    float4 wp = wave_prod_desc(q);
    if (lane == 0) sW[wid] = wp;
    __syncthreads();
    if (tid == 0) {
        float4 a = qmul(sW[1], sW[0]);
        a = qmul(sW[2], a);
        a = qmul(sW[3], a);
        A[blockIdx.x] = qnorm(a);
    }
}

// K2: ONE block, parallel scan of the nblk aggregates.
// Thread owns EPT consecutive entries; EB[idx] = qnorm(A[idx-1]@...@A[0]@q0).
template<int EPT>
__global__ void __launch_bounds__(BLK) pmd_k2(
    const float4* __restrict__ A, float4* __restrict__ EB,
    const float* __restrict__ j0re, const float* __restrict__ j0im, int nblk) {
    __shared__ float4 sW[BLK / 64];
    const int tid = threadIdx.x, lane = tid & 63, wid = tid >> 6;
    const int t0 = tid * EPT;
    float4 excl[EPT];
    float4 run = qid();
    #pragma unroll
    for (int e = 0; e < EPT; ++e) {
        excl[e] = run;
        if (t0 + e < nblk) run = qmul(A[t0 + e], run);
    }
    float4 v = wave_scan_incl(run, lane);
    if (lane == 63) sW[wid] = v;
    __syncthreads();
    float4 P = qid();
    for (int w = 0; w < wid; ++w) P = qmul(sW[w], P);
    float4 vprev = shfl_up4(v, 1);
    float4 texcl = (lane == 0) ? P : qmul(vprev, P);  // product of all earlier threads
    // q0 from J0 = [[w - i v1, -v3 - i v2],[v3 - i v2, w + i v1]]
    float4 q0 = make_float4(j0re[0], -j0im[0], -j0im[1], -j0re[1]);
    float4 base = qmul(texcl, q0);
    #pragma unroll
    for (int e = 0; e < EPT; ++e) {
        if (t0 + e < nblk) EB[t0 + e] = qnorm(qmul(excl[e], base));
    }
}

// K3: chunk quats in registers, wave scan + 1 barrier for the block prefix,
// EB[b] broadcast read, epilogue.
__global__ void __launch_bounds__(BLK) pmd_k3(
    const float* __restrict__ al, const float* __restrict__ sre,
    const float* __restrict__ sim, const float4* __restrict__ EB,
    float* __restrict__ outf, long long T, long long nchunk) {
    __shared__ float4 sW[BLK / 64];
    const int tid = threadIdx.x, lane = tid & 63, wid = tid >> 6;
    const int b = blockIdx.x;
    const long long t = (long long)b * BLK + tid;

    float4 d[CH];
    bool full;
    float4 q = chunk_quats(al, t, T, nchunk, d, full);
    float4 v = wave_scan_incl(q, lane);
    if (lane == 63) sW[wid] = v;
    __syncthreads();
    float4 P = qid();
    for (int w = 0; w < wid; ++w) P = qmul(sW[w], P);
    float4 vprev = shfl_up4(v, 1);
    float4 Xv = (lane == 0) ? P : qmul(vprev, P);
    float4 run = qmul(Xv, EB[b]);   // same addr for all threads -> broadcast
    if (t < nchunk)
        apply_and_store(d, run, full, t, T, sre, sim, outf);
}

// Zero-workspace fallback: one block walks the whole sequence in segments.
__global__ void __launch_bounds__(BLK) pmd_mono(
    const float* __restrict__ al, const float* __restrict__ sre,
    const float* __restrict__ sim, const float* __restrict__ j0re,
    const float* __restrict__ j0im, float* __restrict__ outf, long long T) {
    __shared__ float4 sW[BLK / 64];
    __shared__ float4 sbase;
    const int tid = threadIdx.x, lane = tid & 63, wid = tid >> 6;
    if (tid == 0)
        sbase = make_float4(j0re[0], -j0im[0], -j0im[1], -j0re[1]);
    __syncthreads();
    const long long nchunk = (T + CH - 1) / CH;
    for (long long c0 = 0; c0 < nchunk; c0 += BLK) {
        const long long t = c0 + tid;
        float4 d[CH];
        bool full;
        float4 q = chunk_quats(al, t, T, nchunk, d, full);
        float4 v = wave_scan_incl(q, lane);
        if (lane == 63) sW[wid] = v;
        __syncthreads();
        float4 P = qid();
        for (int w = 0; w < wid; ++w) P = qmul(sW[w], P);
        float4 vprev = shfl_up4(v, 1);
        float4 Xv = (lane == 0) ? P : qmul(vprev, P);
        float4 base = sbase;
        __syncthreads();
        if (tid == BLK - 1) sbase = qnorm(qmul(qmul(v, P), base));
        if (t < nchunk) {
            float4 run = qmul(Xv, base);
            apply_and_store(d, run, full, t, T, sre, sim, outf);
        }
        __syncthreads();
    }
}

extern "C" void kernel_launch(void* const* d_in, const int* in_sizes, int n_in,
                              void* d_out, int out_size, void* d_ws, size_t ws_size,
                              hipStream_t stream) {
    const float* sre  = (const float*)d_in[0];
    const float* sim  = (const float*)d_in[1];
    const float* al   = (const float*)d_in[2];
    const float* j0re = (const float*)d_in[3];
    const float* j0im = (const float*)d_in[4];
    float* outf = (float*)d_out;   // f32 out, real parts [T,2]
    long long T = (long long)in_sizes[2] / 3;
    if (T <= 0) return;

    long long nchunk = (T + CH - 1) / CH;
    long long nblkLL = (nchunk + BLK - 1) / BLK;
    size_t need = (size_t)(2 * nblkLL) * sizeof(float4);

    if (ws_size >= need && nblkLL <= (long long)BLK * 16) {
        int nblk = (int)nblkLL;
        float4* A  = (float4*)d_ws;
        float4* EB = A + nblk;
        pmd_k1<<<nblk, BLK, 0, stream>>>(al, A, T, nchunk);
        if      (nblk <= BLK)      pmd_k2<1> <<<1, BLK, 0, stream>>>(A, EB, j0re, j0im, nblk);
        else if (nblk <= 2 * BLK)  pmd_k2<2> <<<1, BLK, 0, stream>>>(A, EB, j0re, j0im, nblk);
        else if (nblk <= 4 * BLK)  pmd_k2<4> <<<1, BLK, 0, stream>>>(A, EB, j0re, j0im, nblk);
        else if (nblk <= 8 * BLK)  pmd_k2<8> <<<1, BLK, 0, stream>>>(A, EB, j0re, j0im, nblk);
        else                       pmd_k2<16><<<1, BLK, 0, stream>>>(A, EB, j0re, j0im, nblk);
        pmd_k3<<<nblk, BLK, 0, stream>>>(al, sre, sim, EB, outf, T, nchunk);
    } else {
        pmd_mono<<<1, BLK, 0, stream>>>(al, sre, sim, j0re, j0im, outf, T);
    }
}